// Round 2
// 408.188 us; speedup vs baseline: 1.0155x; 1.0155x over previous
//
#include <hip/hip_runtime.h>
#include <stdint.h>

typedef unsigned short u16;
typedef __attribute__((ext_vector_type(8))) short short8;
typedef __attribute__((ext_vector_type(4))) short s16x4;
typedef __attribute__((ext_vector_type(4))) float f32x4;
typedef __attribute__((ext_vector_type(16))) float f32x16;

__device__ __forceinline__ u16 f2bf(float f) {
  uint32_t x = __float_as_uint(f);
  x += 0x7fff + ((x >> 16) & 1);
  return (u16)(x >> 16);
}
__device__ __forceinline__ float bf2f(u16 u) {
  return __uint_as_float(((uint32_t)u) << 16);
}
__device__ __forceinline__ f32x4 mfma16(short8 a, short8 b, f32x4 c) {
  return __builtin_amdgcn_mfma_f32_16x16x32_bf16(a, b, c, 0, 0, 0);
}
__device__ __forceinline__ f32x16 mfma32(short8 a, short8 b, f32x16 c) {
  return __builtin_amdgcn_mfma_f32_32x32x16_bf16(a, b, c, 0, 0, 0);
}
__device__ __forceinline__ f32x4 mfma16k16(s16x4 a, s16x4 b, f32x4 c) {
  return __builtin_amdgcn_mfma_f32_16x16x16bf16_1k(a, b, c, 0, 0, 0);
}
__device__ __forceinline__ void gld16(const u16* g, u16* l) {
  __builtin_amdgcn_global_load_lds(
      (const __attribute__((address_space(1))) unsigned int*)g,
      (__attribute__((address_space(3))) unsigned int*)l, 16, 0, 0);
}
__device__ __forceinline__ float exp2a(float x) {  // raw v_exp_f32 (2^x)
  float r;
  asm("v_exp_f32 %0, %1" : "=v"(r) : "v"(x));
  return r;
}

#define WAIT_VM(n) asm volatile("s_waitcnt vmcnt(" #n ")" ::: "memory")

// ---------------- fused fp32 -> bf16 conversion (x | Wqkv | Wout) ----------------
__global__ __launch_bounds__(256) void cvt_all(const float* __restrict__ x,
                                               const float* __restrict__ wqkv,
                                               const float* __restrict__ wout,
                                               u16* __restrict__ xb,
                                               u16* __restrict__ wqkvb,
                                               u16* __restrict__ woutb) {
  long i = ((long)blockIdx.x * 256 + threadIdx.x) * 8;
  const float* s;
  u16* d;
  long off;
  if (i < 8388608) {
    s = x; d = xb; off = i;
  } else if (i < 20971520) {
    s = wqkv; d = wqkvb; off = i - 8388608;
  } else {
    s = wout; d = woutb; off = i - 20971520;
  }
  f32x4 a = *(const f32x4*)(s + off);
  f32x4 b = *(const f32x4*)(s + off + 4);
  short8 o;
#pragma unroll
  for (int j = 0; j < 4; j++) {
    o[j] = (short)f2bf(a[j]);
    o[j + 4] = (short)f2bf(b[j]);
  }
  *(short8*)(d + off) = o;
}

// ---------------- QKV GEMM: 256x256 tile, 8 waves, BK=32, 4-ring LDS, counted vmcnt ----
// C = A(4096x2048) * B(6144x2048)^T, both bf16 row-major (BT layout).
// K = 2048 -> 64 K-tiles of BK=32. Deep pipeline: during K-tile tau, stage tile tau+3
// into ring (tau+3)&3 (== ring of tile tau-1, whose LDS reads completed before the
// barrier that ended tile tau-1 -> race-free). Tile-boundary wait vmcnt(8): tiles
// tau+2, tau+3 stay in flight -- never drains to 0 in steady state (T4). Two phases
// of 16 MFMA per K-tile, raw s_barrier, s_setprio around MFMA clusters (T5).
// LDS chunk swizzle (same as gemm_bt): stored 16B chunk at row r, position p holds
// global chunk (p - (r>>1)) & 3. Staging permutes the per-lane GLOBAL source chunk
// (LDS dest stays lane-contiguous as global_load_lds requires); fragment reads use
// position ((quad + (l15>>1)) & 3) -> 16-lane groups land on 8 bank-start positions
// = 2-way aliasing (free) instead of 8-way conflict of the linear layout.
// Epilogue: q (scaled by 1/sqrt(128)*log2e) & k head-major [B,H,T,128] scatter;
//           v transposed per head [B,H,128,T] (8B stores along t).
__global__ __launch_bounds__(512, 2) void gemm_qkv(const u16* __restrict__ A,
                                                   const u16* __restrict__ Bw,
                                                   u16* __restrict__ q3) {
  __shared__ __align__(16) u16 SA[32768];  // 4 rings x [256 rows][32 k] bf16 = 64 KiB
  __shared__ __align__(16) u16 SB[32768];  // 64 KiB
  // bijective XCD swizzle: 384 blocks = 8 XCDs x 48; each XCD owns 3 n-panels x 16 m
  const int id = blockIdx.x;
  const int swz = (id & 7) * 48 + (id >> 3);
  const int by = swz & 15, bx = swz >> 4;
  const int m0 = by * 256, n0 = bx * 256;
  const int t = threadIdx.x, w = t >> 6, lane = t & 63;
  const int quad = lane >> 4, l15 = lane & 15;
  const int wm = w >> 2, wn = w & 3;  // 2 x 4 wave grid; per-wave C = 128 x 64
  // staging: thread t -> row rS = t>>2 (and rS+128), LDS position pS = t&3.
  // source chunk cS = (pS - (rS>>1)) & 3; (rS+128)>>1 adds 64 (== 0 mod 4) -> same cS.
  const int rS = t >> 2, pS = t & 3;
  const int cS = (pS - (rS >> 1)) & 3;
  const size_t arow = (size_t)(m0 + rS) * 2048 + cS * 8;
  const size_t brow = (size_t)(n0 + rS) * 2048 + cS * 8;

#define STAGE_A(kt)                                      \
  {                                                      \
    const u16* ga_ = A + arow + (size_t)(kt) * 32;       \
    u16* la_ = SA + ((kt) & 3) * 8192 + t * 8;           \
    gld16(ga_, la_);                                     \
    gld16(ga_ + (size_t)128 * 2048, la_ + 4096);         \
  }
#define STAGE_B(kt)                                      \
  {                                                      \
    const u16* gb_ = Bw + brow + (size_t)(kt) * 32;      \
    u16* lb_ = SB + ((kt) & 3) * 8192 + t * 8;           \
    gld16(gb_, lb_);                                     \
    gld16(gb_ + (size_t)128 * 2048, lb_ + 4096);         \
  }

  f32x4 acc[8][4] = {};
  // fragment-read swizzled chunk position: rows are base16 + l15 -> (row>>1)&3 ==
  // (l15>>1)&3 for every fragment row in both phases (bases are multiples of 16).
  const int pq = ((quad + (l15 >> 1)) & 3) * 8;

  // prologue: tiles 0,1,2 in flight (12 loads); wait for tile 0 (oldest 4)
  STAGE_A(0); STAGE_B(0);
  STAGE_A(1); STAGE_B(1);
  STAGE_A(2); STAGE_B(2);
  WAIT_VM(8);
  __builtin_amdgcn_s_barrier();

#pragma unroll 1
  for (int tau = 0; tau < 64; ++tau) {
    const u16* Sa = SA + (tau & 3) * 8192;
    const u16* Sb = SB + (tau & 3) * 8192;
    short8 af[4], bfr[4];
    // ---- phase 1: wave rows 0..63, all 64 cols, K=32 ----
#pragma unroll
    for (int i = 0; i < 4; i++)
      af[i] = *(const short8*)&Sa[(wm * 128 + i * 16 + l15) * 32 + pq];
#pragma unroll
    for (int n = 0; n < 4; n++)
      bfr[n] = *(const short8*)&Sb[(wn * 64 + n * 16 + l15) * 32 + pq];
    if (tau < 61) STAGE_A(tau + 3);
    __builtin_amdgcn_s_barrier();
    __builtin_amdgcn_s_setprio(1);
#pragma unroll
    for (int mi = 0; mi < 4; mi++)
#pragma unroll
      for (int ni = 0; ni < 4; ni++)
        acc[mi][ni] = mfma16(af[mi], bfr[ni], acc[mi][ni]);
    __builtin_amdgcn_s_setprio(0);
    __builtin_amdgcn_s_barrier();
    // ---- phase 2: wave rows 64..127 (B frags reused from phase 1) ----
#pragma unroll
    for (int i = 0; i < 4; i++)
      af[i] = *(const short8*)&Sa[(wm * 128 + 64 + i * 16 + l15) * 32 + pq];
    if (tau < 61) STAGE_B(tau + 3);
    __builtin_amdgcn_s_barrier();
    __builtin_amdgcn_s_setprio(1);
#pragma unroll
    for (int mi = 0; mi < 4; mi++)
#pragma unroll
      for (int ni = 0; ni < 4; ni++)
        acc[4 + mi][ni] = mfma16(af[mi], bfr[ni], acc[4 + mi][ni]);
    __builtin_amdgcn_s_setprio(0);
    // counted tile-boundary wait: tile tau+1 must have landed; tiles tau+2, tau+3
    // stay in flight (8 loads). Epilogue drains 8 -> 4 -> 0 at tau = 60/61/62.
    if (tau < 61) {
      WAIT_VM(8);
    } else if (tau == 61) {
      WAIT_VM(4);
    } else if (tau == 62) {
      WAIT_VM(0);
    }
    __builtin_amdgcn_s_barrier();
  }
#undef STAGE_A
#undef STAGE_B

  // ---- epilogue: scatter into q | k | vT (layouts match rope_k / attn_k) ----
  // C row = m0 + wm*128 + mi*16 + quad*4 + r ; C col = n0 + wn*64 + ni*16 + l15
  const int which = n0 >> 11;  // 0=q 1=k 2=v (2048 % 256 == 0 -> block-uniform)
  const int bb = m0 >> 11, tt0 = m0 & 2047;
  if (which == 2) {
    u16* vbase = q3 + 16777216;
#pragma unroll
    for (int ni = 0; ni < 4; ni++) {
      const int gcol = (n0 & 2047) + wn * 64 + ni * 16 + l15;
      const int hh = gcol >> 7, di = gcol & 127;
      u16* vb = vbase + ((size_t)(bb * 16 + hh) * 128 + di) * 2048;
#pragma unroll
      for (int mi = 0; mi < 8; mi++) {
        const int tloc = tt0 + wm * 128 + mi * 16 + quad * 4;
        s16x4 st;
#pragma unroll
        for (int r = 0; r < 4; r++) st[r] = (short)f2bf(acc[mi][ni][r]);
        *(s16x4*)(vb + tloc) = st;  // 4 consecutive t -> 8B store
      }
    }
  } else {
    const float sc = (which == 0) ? 0.1275174f : 1.0f;  // 1/sqrt(128)*log2(e)
    u16* base = q3 + (size_t)which * 8388608;
#pragma unroll
    for (int ni = 0; ni < 4; ni++) {
      const int gcol = (n0 & 2047) + wn * 64 + ni * 16 + l15;
      const int hh = gcol >> 7, di = gcol & 127;
      u16* qb = base + ((size_t)(bb * 16 + hh) * 2048) * 128 + di;
#pragma unroll
      for (int mi = 0; mi < 8; mi++) {
        const int tloc = tt0 + wm * 128 + mi * 16 + quad * 4;
#pragma unroll
        for (int r = 0; r < 4; r++)
          qb[(size_t)(tloc + r) * 128] = f2bf(acc[mi][ni][r] * sc);
      }
    }
  }
}

// ---------------- BT GEMM (kept for the output projection), 32x32x16 MFMA --------
template <int EPI>
__global__ __launch_bounds__(256) void gemm_bt(const u16* __restrict__ A,
                                               const u16* __restrict__ B,
                                               int K, void* __restrict__ Cv, int N) {
  __shared__ __align__(16) u16 SMEM[8448];  // staging 16KB; EPI=1 epilogue f32[32][132]
  u16* As = SMEM;
  u16* Bs = SMEM + 4096;
  const int m0 = blockIdx.y * 128, n0 = blockIdx.x * 128;
  const int t = threadIdx.x, w = t >> 6, lane = t & 63;
  const int l31 = lane & 31, half = lane >> 5;
  const int rb = (w >> 1) * 64, cb = (w & 1) * 64;
  f32x16 acc[2][2] = {};
  const int rowS = w * 16 + (lane >> 2);                // staged row (0..63, +64 second)
  const int cS = ((lane & 3) - (rowS >> 1)) & 3;        // swizzled source chunk
  const u16* ag = A + (size_t)(m0 + rowS) * K + cS * 8;
  const u16* bg = B + (size_t)(n0 + rowS) * K + cS * 8;
  u16* al = As + w * 512 + lane * 8;  // lane-contiguous: base + lane*16B
  u16* bl = Bs + w * 512 + lane * 8;
  const size_t rowskip = (size_t)64 * K;
  const int p0 = ((0 * 2 + half + (l31 >> 1)) & 3) * 8;  // kh=0
  const int p1 = ((1 * 2 + half + (l31 >> 1)) & 3) * 8;  // kh=1
  for (int k0 = 0; k0 < K; k0 += 32) {
    __syncthreads();
    gld16(ag, al);
    gld16(ag + rowskip, al + 2048);
    gld16(bg, bl);
    gld16(bg + rowskip, bl + 2048);
    ag += 32;
    bg += 32;
    __syncthreads();
    short8 af[2][2], bfr[2][2];
#pragma unroll
    for (int mi = 0; mi < 2; mi++) {
      af[mi][0] = *(const short8*)&As[(rb + mi * 32 + l31) * 32 + p0];
      af[mi][1] = *(const short8*)&As[(rb + mi * 32 + l31) * 32 + p1];
    }
#pragma unroll
    for (int ni = 0; ni < 2; ni++) {
      bfr[ni][0] = *(const short8*)&Bs[(cb + ni * 32 + l31) * 32 + p0];
      bfr[ni][1] = *(const short8*)&Bs[(cb + ni * 32 + l31) * 32 + p1];
    }
#pragma unroll
    for (int kh = 0; kh < 2; kh++)
#pragma unroll
      for (int mi = 0; mi < 2; mi++)
#pragma unroll
        for (int ni = 0; ni < 2; ni++)
          acc[mi][ni] = mfma32(af[mi][kh], bfr[ni][kh], acc[mi][ni]);
  }

  if (EPI == 0) {
    const int which = n0 >> 11;
    const int hh = (n0 & 2047) >> 7;
    const int bb = m0 >> 11, tt0 = m0 & 2047;
    u16* q3 = (u16*)Cv;
    if (which == 2) {
      u16* vbase = q3 + 16777216 + ((size_t)(bb * 16 + hh) * 128) * 2048;
#pragma unroll
      for (int mi = 0; mi < 2; mi++)
#pragma unroll
        for (int ni = 0; ni < 2; ni++) {
          int di = cb + ni * 32 + l31;
          int trow = tt0 + rb + mi * 32 + half * 4;
#pragma unroll
          for (int rg2 = 0; rg2 < 4; rg2++) {
            s16x4 st;
#pragma unroll
            for (int j = 0; j < 4; j++) st[j] = (short)f2bf(acc[mi][ni][rg2 * 4 + j]);
            *(s16x4*)(vbase + (size_t)di * 2048 + trow + rg2 * 8) = st;
          }
        }
    } else {
      const float sc = (which == 0) ? 0.1275174f : 1.0f;
      u16* base = q3 + (size_t)which * 8388608 + ((size_t)(bb * 16 + hh) * 2048) * 128;
#pragma unroll
      for (int mi = 0; mi < 2; mi++)
#pragma unroll
        for (int ni = 0; ni < 2; ni++) {
          int di = cb + ni * 32 + l31;
          int trow = tt0 + rb + mi * 32 + half * 4;
#pragma unroll
          for (int reg = 0; reg < 16; reg++) {
            int tt = trow + (reg & 3) + 8 * (reg >> 2);
            base[(size_t)tt * 128 + di] = f2bf(acc[mi][ni][reg] * sc);
          }
        }
    }
  } else {
    float* Es = (float*)SMEM;  // [32][132]
    float* C = (float*)Cv;
#pragma unroll
    for (int r = 0; r < 4; r++) {
      __syncthreads();
      if ((w >> 1) == (r >> 1)) {
        const int mi = r & 1;
#pragma unroll
        for (int ni = 0; ni < 2; ni++) {
          int col = cb + ni * 32 + l31;
#pragma unroll
          for (int reg = 0; reg < 16; reg++) {
            int lrow = (reg & 3) + 8 * (reg >> 2) + half * 4;
            Es[lrow * 132 + col] = acc[mi][ni][reg];
          }
        }
      }
      __syncthreads();
#pragma unroll
      for (int it = 0; it < 4; it++) {
        int idx = it * 256 + t;
        int row = idx >> 5, ch = idx & 31;
        f32x4 vv = *(const f32x4*)&Es[row * 132 + ch * 4];
        *(f32x4*)&C[(size_t)(m0 + r * 32 + row) * N + n0 + ch * 4] = vv;
      }
    }
  }
}

// ---------------- RoPE in-place on q,k (heads 0..7 only) ----------------
__global__ __launch_bounds__(256) void rope_k(u16* __restrict__ q, u16* __restrict__ k,
                                              const float* __restrict__ cosT,
                                              const float* __restrict__ sinT) {
  int t = threadIdx.x;
  int row = blockIdx.x * 4 + (t >> 6);  // over (b, h<8, tpos)
  int i = t & 63;
  int b = row >> 14;
  int h = (row >> 11) & 7;
  int tp = row & 2047;
  size_t base = ((size_t)((b * 16 + h) * 2048 + tp)) * 128 + 2 * i;
  float c = cosT[tp * 64 + i], s = sinT[tp * 64 + i];
  {
    uint32_t u = *(uint32_t*)(q + base);
    float x0 = bf2f((u16)(u & 0xffff)), x1 = bf2f((u16)(u >> 16));
    float re = x0 * c - x1 * s, im = x0 * s + x1 * c;
    *(uint32_t*)(q + base) = (uint32_t)f2bf(re) | ((uint32_t)f2bf(im) << 16);
  }
  {
    uint32_t u = *(uint32_t*)(k + base);
    float x0 = bf2f((u16)(u & 0xffff)), x1 = bf2f((u16)(u >> 16));
    float re = x0 * c - x1 * s, im = x0 * s + x1 * c;
    *(uint32_t*)(k + base) = (uint32_t)f2bf(re) | ((uint32_t)f2bf(im) << 16);
  }
}

// ---------------- flash attention, S^T orientation ----------------
__global__ __launch_bounds__(256, 2) void attn_k(const u16* __restrict__ qh,
                                                 const u16* __restrict__ kh,
                                                 const u16* __restrict__ vTh,
                                                 u16* __restrict__ attno) {
  __shared__ __align__(16) u16 Ks[8192];  // 64 keys x 128 d, XOR-swizzled 16B chunks
  __shared__ __align__(16) u16 Vt[8192];  // 128 d x 64 keys, XOR-swizzled 16B chunks
  const int i = blockIdx.x;
  const int jj = i & 255, half = i >> 8;
  const int bh = jj >> 3, t8 = jj & 7;
  const int qt = half ? (15 - t8) : t8;
  const int q0 = qt * 128;
  const int t = threadIdx.x, w = t >> 6, lane = t & 63;
  const int quad = lane >> 4, l15 = lane & 15;
  const size_t bhoff = (size_t)bh * 262144;

  short8 qb[2][4];
  {
    const u16* qp = qh + bhoff + (size_t)(q0 + w * 32 + l15) * 128 + quad * 8;
#pragma unroll
    for (int qq = 0; qq < 2; qq++)
#pragma unroll
      for (int ks = 0; ks < 4; ks++)
        qb[qq][ks] = *(const short8*)(qp + qq * 2048 + ks * 32);
  }
  f32x4 of[2][8] = {};
  float mst[2] = {-1e30f, -1e30f}, lst[2] = {0.f, 0.f};
  const int nkt = 2 * qt + 2;
  const int wq0 = q0 + w * 32;

  for (int kt = 0; kt < nkt; kt++) {
    const int k0 = kt * 64;
    __syncthreads();
    {
#pragma unroll
      for (int it = 0; it < 4; it++) {  // K: 64 rows x 16 chunks
        int L = it * 256 + t;
        int key = L >> 4, c = L & 15;
        gld16(kh + bhoff + (size_t)(k0 + key) * 128 + ((c ^ (key & 15)) * 8),
              Ks + (size_t)L * 8);
      }
#pragma unroll
      for (int it = 0; it < 4; it++) {  // V^T: 128 rows x 8 chunks
        int L = it * 256 + t;
        int d = L >> 3, c = L & 7;
        gld16(vTh + bhoff + (size_t)d * 2048 + k0 + ((c ^ (d & 7)) * 8),
              Vt + (size_t)L * 8);
      }
    }
    __syncthreads();
    if (k0 <= wq0 + 31) {
      f32x4 sacc[2][4];
#pragma unroll
      for (int qq = 0; qq < 2; qq++)
#pragma unroll
        for (int kk = 0; kk < 4; kk++) sacc[qq][kk] = (f32x4){0.f, 0.f, 0.f, 0.f};
#pragma unroll
      for (int kk = 0; kk < 4; kk++) {
        short8 kf[4];
#pragma unroll
        for (int ks = 0; ks < 4; ks++)
          kf[ks] = *(const short8*)&Ks[(kk * 16 + l15) * 128 + ((ks * 4 + quad) ^ l15) * 8];
#pragma unroll
        for (int qq = 0; qq < 2; qq++)
#pragma unroll
          for (int ks = 0; ks < 4; ks++)
            sacc[qq][kk] = mfma16(kf[ks], qb[qq][ks], sacc[qq][kk]);
      }
      const bool needmask = (k0 + 63 > wq0);
      s16x4 pf[2][4];
      float alpha[2];
#pragma unroll
      for (int qq = 0; qq < 2; qq++) {
        const int qg = wq0 + qq * 16 + l15;
        if (needmask) {
#pragma unroll
          for (int kk = 0; kk < 4; kk++)
#pragma unroll
            for (int rg = 0; rg < 4; rg++)
              if (k0 + kk * 16 + quad * 4 + rg > qg) sacc[qq][kk][rg] = -1e30f;
        }
        float pm = -1e30f;
#pragma unroll
        for (int kk = 0; kk < 4; kk++)
#pragma unroll
          for (int rg = 0; rg < 4; rg++) pm = fmaxf(pm, sacc[qq][kk][rg]);
        pm = fmaxf(pm, __shfl_xor(pm, 16));
        pm = fmaxf(pm, __shfl_xor(pm, 32));
        float mnew = fmaxf(mst[qq], pm);
        alpha[qq] = exp2a(mst[qq] - mnew);
        mst[qq] = mnew;
        float ps = 0.f;
#pragma unroll
        for (int kk = 0; kk < 4; kk++) {
          float e0 = exp2a(sacc[qq][kk][0] - mnew);
          float e1 = exp2a(sacc[qq][kk][1] - mnew);
          float e2 = exp2a(sacc[qq][kk][2] - mnew);
          float e3 = exp2a(sacc[qq][kk][3] - mnew);
          ps += (e0 + e1) + (e2 + e3);
          pf[qq][kk][0] = (short)f2bf(e0);
          pf[qq][kk][1] = (short)f2bf(e1);
          pf[qq][kk][2] = (short)f2bf(e2);
          pf[qq][kk][3] = (short)f2bf(e3);
        }
        ps += __shfl_xor(ps, 16);
        ps += __shfl_xor(ps, 32);
        lst[qq] = lst[qq] * alpha[qq] + ps;
      }
#pragma unroll
      for (int qq = 0; qq < 2; qq++) {
        if (!__all(alpha[qq] == 1.0f)) {
          float a = alpha[qq];
#pragma unroll
          for (int df = 0; df < 8; df++) of[qq][df] *= a;
        }
      }
#pragma unroll
      for (int df = 0; df < 8; df++) {
        s16x4 vf[4];
#pragma unroll
        for (int kk = 0; kk < 4; kk++)
          vf[kk] = *(const s16x4*)&Vt[(df * 16 + l15) * 64 +
                                      ((kk * 2 + (quad >> 1)) ^ (l15 & 7)) * 8 +
                                      (quad & 1) * 4];
#pragma unroll
        for (int qq = 0; qq < 2; qq++)
#pragma unroll
          for (int kk = 0; kk < 4; kk++)
            of[qq][df] = mfma16k16(vf[kk], pf[qq][kk], of[qq][df]);
      }
    }
  }
  const int b = bh >> 4, h = bh & 15;
#pragma unroll
  for (int qq = 0; qq < 2; qq++) {
    float linv = 1.0f / lst[qq];
    const size_t row = (size_t)(b * 2048 + q0 + w * 32 + qq * 16 + l15);
#pragma unroll
    for (int df = 0; df < 8; df++) {
      s16x4 o;
#pragma unroll
      for (int rg = 0; rg < 4; rg++) o[rg] = (short)f2bf(of[qq][df][rg] * linv);
      *(s16x4*)(attno + row * 2048 + h * 128 + df * 16 + quad * 4) = o;
    }
  }
}

extern "C" void kernel_launch(void* const* d_in, const int* in_sizes, int n_in,
                              void* d_out, int out_size, void* d_ws, size_t ws_size,
                              hipStream_t stream) {
  const float* x = (const float*)d_in[0];
  const float* Wqkv = (const float*)d_in[1];
  const float* Wout = (const float*)d_in[2];
  const float* cosT = (const float*)d_in[3];
  const float* sinT = (const float*)d_in[4];
  float* out = (float*)d_out;
  char* ws = (char*)d_ws;
  // workspace (96 MiB), lifetime-based reuse:
  //   [0,        50331648)  qkvh: q | k | vT (vT = per-head transposed v)
  //   [50331648, 58720256)  woutb (persists to gemm2)
  //   [58720256, 75497472)  xb (dead after gemm1)
  //   [75497472,100663296)  wqkvb (dead after gemm1) -> reused as attno
  u16* qkvh = (u16*)(ws + 0);
  u16* woutb = (u16*)(ws + 50331648);
  u16* xb = (u16*)(ws + 58720256);
  u16* wqkvb = (u16*)(ws + 75497472);
  u16* attno = wqkvb;

  cvt_all<<<12288, 256, 0, stream>>>(x, Wqkv, Wout, xb, wqkvb, woutb);
  gemm_qkv<<<384, 512, 0, stream>>>(xb, wqkvb, qkvh);
  rope_k<<<8192, 256, 0, stream>>>(qkvh, qkvh + 8388608, cosT, sinT);
  attn_k<<<512, 256, 0, stream>>>(qkvh, qkvh + 8388608, qkvh + 16777216, attno);
  gemm_bt<1><<<dim3(16, 32), 256, 0, stream>>>(attno, woutb, 2048, (void*)out, 2048);
}